// Round 11
// baseline (181.068 us; speedup 1.0000x reference)
//
#include <hip/hip_runtime.h>
#include <hip/hip_bf16.h>
#include <math.h>

// Problem constants
#define NROI   512
#define CCH    256
#define POOLP  7
#define DDIM   12544   // 256*7*7
#define HIDN   1024
#define NCLS   81
#define NREG   324
#define NHEAD  512           // padded head N: 81 cls + 324 reg + 107 pad
#define OUT_ROIS   2560      // 2*256*5
#define OUT_CLS    (512*81)

typedef __attribute__((ext_vector_type(4))) float f32x4;
typedef __attribute__((ext_vector_type(8))) short bf16x8;

static __device__ __forceinline__ unsigned short f2bf(float x) {
    __hip_bfloat16 h = __float2bfloat16(x);
    return *reinterpret_cast<unsigned short*>(&h);
}
static __device__ __forceinline__ float bf2f(unsigned short u) {
    unsigned int b = ((unsigned int)u) << 16;
    return *reinterpret_cast<float*>(&b);
}

// ---------------------------------------------------------------------------
// prep: [0,10) rois | [10,266) zero hf (1MB) | [266,1290) w2 cvt
//       | [1290,2314) head pack | [2314,3338) w1 permute
#define PS_B0 10
#define PS_B1 (PS_B0 + 256)
#define PS_B2 (PS_B1 + 1024)
#define PS_B3 (PS_B2 + 1024)
#define PS_B4 (PS_B3 + 1024)
__global__ __launch_bounds__(256) void prep_k(const float* __restrict__ rois,
                                              const float* __restrict__ w1,
                                              const float* __restrict__ w2,
                                              const float* __restrict__ wc,
                                              const float* __restrict__ wr,
                                              float* __restrict__ out,
                                              float* __restrict__ hf,
                                              unsigned short* __restrict__ w1b,
                                              unsigned short* __restrict__ w2b,
                                              unsigned short* __restrict__ whd) {
    __shared__ unsigned short lw[49 * 258];   // used by permute range only
    int bid = blockIdx.x, t = threadIdx.x;
    if (bid < PS_B0) {
        int i = bid * 256 + t;
        if (i < OUT_ROIS) out[i] = rois[i];
    } else if (bid < PS_B1) {
        int i = (bid - PS_B0) * 256 + t;              // float4, 65536 total
        ((float4*)hf)[i] = make_float4(0.f, 0.f, 0.f, 0.f);
    } else if (bid < PS_B2) {
        int i = (bid - PS_B1) * 256 + t;              // float4, 262144 total
        float4 v = ((const float4*)w2)[i];
        ushort4 o;
        o.x = f2bf(v.x); o.y = f2bf(v.y); o.z = f2bf(v.z); o.w = f2bf(v.w);
        ((ushort4*)w2b)[i] = o;
    } else if (bid < PS_B3) {
        int i2 = (bid - PS_B2) * 256 + t;             // ushort2, 262144 total
        int r = i2 >> 9, c = (i2 & 511) << 1;
        float v0, v1;
        if (r < NCLS)             { v0 = wc[r * HIDN + c]; v1 = wc[r * HIDN + c + 1]; }
        else if (r < NCLS + NREG) { v0 = wr[(r - NCLS) * HIDN + c]; v1 = wr[(r - NCLS) * HIDN + c + 1]; }
        else                      { v0 = 0.f; v1 = 0.f; }
        ((unsigned int*)whd)[i2] = (unsigned int)f2bf(v0) | ((unsigned int)f2bf(v1) << 16);
    } else {
        // w1 permute: w1b[n][s*256+c] = w1[n][c*49+s]
        int n = bid - PS_B3;
        const float* src = w1 + (size_t)n * DDIM;
        for (int k = t; k < DDIM; k += 256) {
            int c = k / 49;
            int s = k - c * 49;
            lw[s * 258 + c] = f2bf(src[k]);
        }
        __syncthreads();
        unsigned int* dst = (unsigned int*)(w1b + (size_t)n * DDIM);
        for (int j2 = t; j2 < DDIM / 2; j2 += 256) {
            int s = j2 >> 7, c2 = (j2 & 127) << 1;
            dst[j2] = lw[s * 258 + c2] | ((unsigned int)lw[s * 258 + c2 + 1] << 16);
        }
    }
}

// ---------------------------------------------------------------------------
// NCHW fp32 -> NHWC bf16 transpose v5: tile 128 s x 64 c, bf16 LDS 16.9 KB
// (8 blocks/CU) + 512B read segments + XOR-swizzled LDS (conflict-free).
// x: [0,313) p2 | [313,392) p3 | [392,412) p4 | [412,417) p5 ; y: c-tile ; z: b
__global__ __launch_bounds__(256) void transpose_k(const float* __restrict__ p2,
                                                   const float* __restrict__ p3,
                                                   const float* __restrict__ p4,
                                                   const float* __restrict__ p5,
                                                   unsigned short* __restrict__ f0,
                                                   unsigned short* __restrict__ f1,
                                                   unsigned short* __restrict__ f2,
                                                   unsigned short* __restrict__ f3) {
    __shared__ unsigned short sm[128][66];
    int idx = blockIdx.x;
    const float* in; unsigned short* op; int S, base;
    if (idx < 313)      { in = p2; op = f0; S = 40000; base = 0; }
    else if (idx < 392) { in = p3; op = f1; S = 10000; base = 313; }
    else if (idx < 412) { in = p4; op = f2; S = 2500;  base = 392; }
    else                { in = p5; op = f3; S = 625;   base = 412; }
    int s0 = (idx - base) * 128;
    int c0 = blockIdx.y * 64;
    int b  = blockIdx.z;
    int t  = threadIdx.x;

    int k = t & 31, g = t >> 5;
    bool vec = (s0 + 128 <= S);
#pragma unroll
    for (int jj = 0; jj < 8; jj++) {
        int c = g + jj * 8;
        const float* src = in + ((size_t)(b * CCH + c0 + c)) * S + s0 + k * 4;
        if (vec) {
            float4 v = *(const float4*)src;
#pragma unroll
            for (int e = 0; e < 4; e++) {
                int s = k * 4 + e;
                float val = (e == 0) ? v.x : (e == 1) ? v.y : (e == 2) ? v.z : v.w;
                sm[s][c ^ ((s & 7) << 3)] = f2bf(val);
            }
        } else {
#pragma unroll
            for (int e = 0; e < 4; e++) {
                int s = k * 4 + e;
                sm[s][c ^ ((s & 7) << 3)] =
                    (s0 + s < S) ? f2bf(src[e]) : (unsigned short)0;
            }
        }
    }
    __syncthreads();

    int lane = t & 63, w = t >> 6;
    int rl = lane >> 4, cw = (lane & 15) * 4;
#pragma unroll
    for (int i = 0; i < 8; i++) {
        int s = w * 32 + i * 4 + rl;
        if (s0 + s < S) {
            int sw = (s & 7) << 3;
            unsigned short u0 = sm[s][(cw + 0) ^ sw];
            unsigned short u1 = sm[s][(cw + 1) ^ sw];
            unsigned short u2 = sm[s][(cw + 2) ^ sw];
            unsigned short u3 = sm[s][(cw + 3) ^ sw];
            uint2 v;
            v.x = (unsigned int)u0 | ((unsigned int)u1 << 16);
            v.y = (unsigned int)u2 | ((unsigned int)u3 << 16);
            *(uint2*)(op + ((size_t)b * S + s0 + s) * CCH + c0 + cw) = v;
        }
    }
}

// ---------------------------------------------------------------------------
// ROI Align, block per (py, roi), 256 threads = channels, bf16 NHWC features.
__global__ __launch_bounds__(256) void roi_align_k(const unsigned short* __restrict__ f0,
                                                   const unsigned short* __restrict__ f1,
                                                   const unsigned short* __restrict__ f2,
                                                   const unsigned short* __restrict__ f3,
                                                   const float* __restrict__ rois,
                                                   unsigned short* __restrict__ xpool) {
    __shared__ float s_f[16];
    __shared__ int   s_lo[16], s_hi[16], s_v[16];

    int py = blockIdx.x, r = blockIdx.y, t = threadIdx.x;

    float r0  = rois[r * 5 + 0];
    float rx1 = rois[r * 5 + 1], ry1 = rois[r * 5 + 2];
    float rx2 = rois[r * 5 + 3], ry2 = rois[r * 5 + 4];
    int b = (int)r0;

    float aw = rx2 - rx1 + 1.f, ah = ry2 - ry1 + 1.f;
    float lvf = floorf(log2f(sqrtf(ah * aw) / 56.f + 1e-6f));
    int lv = (int)fminf(fmaxf(lvf, 0.f), 3.f);

    const unsigned short* F = (lv == 0) ? f0 : (lv == 1) ? f1 : (lv == 2) ? f2 : f3;
    int HW      = (lv == 0) ? 200 : (lv == 1) ? 100 : (lv == 2) ? 50 : 25;
    float scale = (lv == 0) ? 0.25f : (lv == 1) ? 0.125f : (lv == 2) ? 0.0625f : 0.03125f;

    float x1 = rx1 * scale, yy1 = ry1 * scale;
    float x2 = rx2 * scale, yy2 = ry2 * scale;
    float rw = fmaxf(x2 - x1, 1.f), rh = fmaxf(yy2 - yy1, 1.f);

    if (t < 16) {
        bool isY = t < 2;
        float coord;
        if (isY) {
            float g = (float)py + ((float)t + 0.5f) * 0.5f;
            coord = yy1 + g * (rh * (1.f / 7.f));
        } else {
            int j = t - 2;
            float g = (float)(j >> 1) + ((float)(j & 1) + 0.5f) * 0.5f;
            coord = x1 + g * (rw * (1.f / 7.f));
        }
        int vld = (coord >= -1.f && coord <= (float)HW) ? 1 : 0;
        float c = fminf(fmaxf(coord, 0.f), (float)(HW - 1));
        int lo  = (int)floorf(c);
        int hi  = min(lo + 1, HW - 1);
        s_v[t] = vld; s_lo[t] = lo; s_hi[t] = hi; s_f[t] = c - (float)lo;
    }
    __syncthreads();

    const unsigned short* Fb = F + ((size_t)b * HW * HW) * CCH + t;
    size_t obase = (size_t)r * DDIM + py * 7 * 256 + t;

    for (int px = 0; px < POOLP; px++) {
        float acc = 0.f;
#pragma unroll
        for (int s = 0; s < 4; s++) {
            int iy = s >> 1;
            int ix = px * 2 + (s & 1);
            int vy = s_v[iy], vx = s_v[2 + ix];
            if (vy & vx) {
                float fy = s_f[iy], fx = s_f[2 + ix];
                int ylo = s_lo[iy], yhi = s_hi[iy];
                int xlo = s_lo[2 + ix], xhi = s_hi[2 + ix];
                float v00 = bf2f(Fb[((size_t)ylo * HW + xlo) * CCH]);
                float v01 = bf2f(Fb[((size_t)ylo * HW + xhi) * CCH]);
                float v10 = bf2f(Fb[((size_t)yhi * HW + xlo) * CCH]);
                float v11 = bf2f(Fb[((size_t)yhi * HW + xhi) * CCH]);
                acc += (1.f - fy) * ((1.f - fx) * v00 + fx * v01)
                     + fy * ((1.f - fx) * v10 + fx * v11);
            }
        }
        xpool[obase + px * 256] = f2bf(acc * 0.25f);
    }
}

// NCHW fp32 fallback (only if ws too small for NHWC staging)
__global__ __launch_bounds__(256) void roi_align_nchw_k(const float* __restrict__ f0,
                                                        const float* __restrict__ f1,
                                                        const float* __restrict__ f2,
                                                        const float* __restrict__ f3,
                                                        const float* __restrict__ rois,
                                                        unsigned short* __restrict__ xpool) {
    __shared__ float s_f[16];
    __shared__ int   s_lo[16], s_hi[16], s_v[16];
    int py = blockIdx.x, r = blockIdx.y, t = threadIdx.x;
    float r0  = rois[r * 5 + 0];
    float rx1 = rois[r * 5 + 1], ry1 = rois[r * 5 + 2];
    float rx2 = rois[r * 5 + 3], ry2 = rois[r * 5 + 4];
    int b = (int)r0;
    float aw = rx2 - rx1 + 1.f, ah = ry2 - ry1 + 1.f;
    float lvf = floorf(log2f(sqrtf(ah * aw) / 56.f + 1e-6f));
    int lv = (int)fminf(fmaxf(lvf, 0.f), 3.f);
    const float* F = (lv == 0) ? f0 : (lv == 1) ? f1 : (lv == 2) ? f2 : f3;
    int HW      = (lv == 0) ? 200 : (lv == 1) ? 100 : (lv == 2) ? 50 : 25;
    float scale = (lv == 0) ? 0.25f : (lv == 1) ? 0.125f : (lv == 2) ? 0.0625f : 0.03125f;
    float x1 = rx1 * scale, yy1 = ry1 * scale;
    float x2 = rx2 * scale, yy2 = ry2 * scale;
    float rw = fmaxf(x2 - x1, 1.f), rh = fmaxf(yy2 - yy1, 1.f);
    if (t < 16) {
        bool isY = t < 2;
        float coord;
        if (isY) {
            float g = (float)py + ((float)t + 0.5f) * 0.5f;
            coord = yy1 + g * (rh * (1.f / 7.f));
        } else {
            int j = t - 2;
            float g = (float)(j >> 1) + ((float)(j & 1) + 0.5f) * 0.5f;
            coord = x1 + g * (rw * (1.f / 7.f));
        }
        int vld = (coord >= -1.f && coord <= (float)HW) ? 1 : 0;
        float c = fminf(fmaxf(coord, 0.f), (float)(HW - 1));
        int lo  = (int)floorf(c);
        int hi  = min(lo + 1, HW - 1);
        s_v[t] = vld; s_lo[t] = lo; s_hi[t] = hi; s_f[t] = c - (float)lo;
    }
    __syncthreads();
    const float* Fb = F + ((size_t)b * CCH + t) * HW * HW;
    size_t obase = (size_t)r * DDIM + py * 7 * 256 + t;
    for (int px = 0; px < POOLP; px++) {
        float acc = 0.f;
#pragma unroll
        for (int s = 0; s < 4; s++) {
            int iy = s >> 1, ix = px * 2 + (s & 1);
            int vy = s_v[iy], vx = s_v[2 + ix];
            if (vy & vx) {
                float fy = s_f[iy], fx = s_f[2 + ix];
                int ylo = s_lo[iy], yhi = s_hi[iy];
                int xlo = s_lo[2 + ix], xhi = s_hi[2 + ix];
                float v00 = Fb[(size_t)ylo * HW + xlo];
                float v01 = Fb[(size_t)ylo * HW + xhi];
                float v10 = Fb[(size_t)yhi * HW + xlo];
                float v11 = Fb[(size_t)yhi * HW + xhi];
                acc += (1.f - fy) * ((1.f - fx) * v00 + fx * v01)
                     + fy * ((1.f - fx) * v10 + fx * v11);
            }
        }
        xpool[obase + px * 256] = f2bf(acc * 0.25f);
    }
}

// ---------------------------------------------------------------------------
// 64x64 bf16 MFMA GEMM, double-buffered, atomic split-K (head).
__global__ __launch_bounds__(256) void gemm_bf16_k(const unsigned short* __restrict__ A,
                                                   const unsigned short* __restrict__ W,
                                                   float* __restrict__ Cacc,
                                                   int M, int N, int K, int kchunk) {
    __shared__ __align__(16) unsigned short As[2][8][64][8];
    __shared__ __align__(16) unsigned short Ws[2][8][64][8];

    int t = threadIdx.x;
    int lane = t & 63, wid = t >> 6;
    int m0 = blockIdx.y * 64, n0 = blockIdx.x * 64;
    int k0 = blockIdx.z * kchunk;
    int wm = (wid >> 1) * 32, wn = (wid & 1) * 32;
    int fr = lane & 15, kg = lane >> 4;
    int nsteps = kchunk >> 6;

    f32x4 acc[2][2] = {};

    const unsigned short* Arow = A + (size_t)(m0 + lane) * K;
    const unsigned short* Wrow = W + (size_t)(n0 + lane) * K;

    auto stage = [&](int buf, int kb) {
#pragma unroll
        for (int i = 0; i < 2; i++) {
            int c = wid * 2 + i;
            __builtin_amdgcn_global_load_lds(
                (const __attribute__((address_space(1))) void*)(Arow + kb + c * 8),
                (__attribute__((address_space(3))) void*)(&As[buf][c][0][0]), 16, 0, 0);
            __builtin_amdgcn_global_load_lds(
                (const __attribute__((address_space(1))) void*)(Wrow + kb + c * 8),
                (__attribute__((address_space(3))) void*)(&Ws[buf][c][0][0]), 16, 0, 0);
        }
    };

    stage(0, k0);
    __syncthreads();
    int cur = 0;
    for (int tt = 0; tt < nsteps; ++tt) {
        if (tt + 1 < nsteps) stage(cur ^ 1, k0 + (tt + 1) * 64);
#pragma unroll
        for (int h = 0; h < 2; h++) {
            bf16x8 a0 = *(const bf16x8*)(&As[cur][h * 4 + kg][wm + fr][0]);
            bf16x8 a1 = *(const bf16x8*)(&As[cur][h * 4 + kg][wm + 16 + fr][0]);
            bf16x8 b0 = *(const bf16x8*)(&Ws[cur][h * 4 + kg][wn + fr][0]);
            bf16x8 b1 = *(const bf16x8*)(&Ws[cur][h * 4 + kg][wn + 16 + fr][0]);
            acc[0][0] = __builtin_amdgcn_mfma_f32_16x16x32_bf16(a0, b0, acc[0][0], 0, 0, 0);
            acc[0][1] = __builtin_amdgcn_mfma_f32_16x16x32_bf16(a0, b1, acc[0][1], 0, 0, 0);
            acc[1][0] = __builtin_amdgcn_mfma_f32_16x16x32_bf16(a1, b0, acc[1][0], 0, 0, 0);
            acc[1][1] = __builtin_amdgcn_mfma_f32_16x16x32_bf16(a1, b1, acc[1][1], 0, 0, 0);
        }
        __syncthreads();
        cur ^= 1;
    }

    int row = m0 + wm + (lane >> 4) * 4;
    int col = n0 + wn + fr;
#pragma unroll
    for (int fm = 0; fm < 2; fm++)
#pragma unroll
        for (int fn = 0; fn < 2; fn++)
#pragma unroll
            for (int r = 0; r < 4; r++)
                atomicAdd(&Cacc[(size_t)(row + fm * 16 + r) * N + col + fn * 16],
                          acc[fm][fn][r]);
}

// ---------------------------------------------------------------------------
// FC2: single-K 64x64 GEMM with fused bias+relu+bf16 epilogue.
__global__ __launch_bounds__(256) void gemm_fc2_k(const unsigned short* __restrict__ A,
                                                  const unsigned short* __restrict__ W,
                                                  const float* __restrict__ bias,
                                                  unsigned short* __restrict__ dst,
                                                  int M, int N, int K) {
    __shared__ __align__(16) unsigned short As[2][8][64][8];
    __shared__ __align__(16) unsigned short Ws[2][8][64][8];

    int t = threadIdx.x;
    int lane = t & 63, wid = t >> 6;
    int m0 = blockIdx.y * 64, n0 = blockIdx.x * 64;
    int wm = (wid >> 1) * 32, wn = (wid & 1) * 32;
    int fr = lane & 15, kg = lane >> 4;
    int nsteps = K >> 6;

    f32x4 acc[2][2] = {};

    const unsigned short* Arow = A + (size_t)(m0 + lane) * K;
    const unsigned short* Wrow = W + (size_t)(n0 + lane) * K;

    auto stage = [&](int buf, int kb) {
#pragma unroll
        for (int i = 0; i < 2; i++) {
            int c = wid * 2 + i;
            __builtin_amdgcn_global_load_lds(
                (const __attribute__((address_space(1))) void*)(Arow + kb + c * 8),
                (__attribute__((address_space(3))) void*)(&As[buf][c][0][0]), 16, 0, 0);
            __builtin_amdgcn_global_load_lds(
                (const __attribute__((address_space(1))) void*)(Wrow + kb + c * 8),
                (__attribute__((address_space(3))) void*)(&Ws[buf][c][0][0]), 16, 0, 0);
        }
    };

    stage(0, 0);
    __syncthreads();
    int cur = 0;
    for (int tt = 0; tt < nsteps; ++tt) {
        if (tt + 1 < nsteps) stage(cur ^ 1, (tt + 1) * 64);
#pragma unroll
        for (int h = 0; h < 2; h++) {
            bf16x8 a0 = *(const bf16x8*)(&As[cur][h * 4 + kg][wm + fr][0]);
            bf16x8 a1 = *(const bf16x8*)(&As[cur][h * 4 + kg][wm + 16 + fr][0]);
            bf16x8 b0 = *(const bf16x8*)(&Ws[cur][h * 4 + kg][wn + fr][0]);
            bf16x8 b1 = *(const bf16x8*)(&Ws[cur][h * 4 + kg][wn + 16 + fr][0]);
            acc[0][0] = __builtin_amdgcn_mfma_f32_16x16x32_bf16(a0, b0, acc[0][0], 0, 0, 0);
            acc[0][1] = __builtin_amdgcn_mfma_f32_16x16x32_bf16(a0, b1, acc[0][1], 0, 0, 0);
            acc[1][0] = __builtin_amdgcn_mfma_f32_16x16x32_bf16(a1, b0, acc[1][0], 0, 0, 0);
            acc[1][1] = __builtin_amdgcn_mfma_f32_16x16x32_bf16(a1, b1, acc[1][1], 0, 0, 0);
        }
        __syncthreads();
        cur ^= 1;
    }

    int row = m0 + wm + (lane >> 4) * 4;
    int col = n0 + wn + fr;
#pragma unroll
    for (int fm = 0; fm < 2; fm++)
#pragma unroll
        for (int fn = 0; fn < 2; fn++) {
            float bv = bias[col + fn * 16];
#pragma unroll
            for (int r = 0; r < 4; r++) {
                float v = fmaxf(acc[fm][fn][r] + bv, 0.f);
                dst[(size_t)(row + fm * 16 + r) * N + col + fn * 16] = f2bf(v);
            }
        }
}

// ---------------------------------------------------------------------------
// FC1 GEMM: BM=64, BN=128, BK=64, 3-buffer depth-2 pipeline with COUNTED
// vmcnt (T3/T4): stages t+1,t+2 stay in flight across barriers; never drain
// to 0 in the main loop. LDS 72KB -> 2 blocks/CU. Split-K 14 partials,
// XCD swizzle keeps one B-panel per XCD. grid = 896 linear blocks.
__global__ __launch_bounds__(256) void gemm128_bf16_k(const unsigned short* __restrict__ A,
                                                      const unsigned short* __restrict__ W,
                                                      float* __restrict__ Cp,
                                                      int M, int N, int K, int kchunk) {
    __shared__ __align__(16) unsigned short As[3][8][64][8];    // 3 x 8 KB
    __shared__ __align__(16) unsigned short Ws[3][8][128][8];   // 3 x 16 KB

    int lin  = blockIdx.x;
    int nb   = (lin & 7) * 112 + (lin >> 3);   // 896 = 8 XCD x 112, bijective
    int tile = nb / 14, bz = nb - tile * 14;   // z innermost per tile
    int bx = tile >> 3, by = tile & 7;         // XCD owns one bx (B-panel)

    int t = threadIdx.x;
    int lane = t & 63, wid = t >> 6;
    int m0 = by * 64, n0 = bx * 128;
    int k0 = bz * kchunk;
    int wm = (wid >> 1) * 32, wn = (wid & 1) * 64;
    int fr = lane & 15, kg = lane >> 4;
    int nsteps = kchunk >> 6;   // 14 (>= 3 required)

    f32x4 acc[2][4] = {};

    const unsigned short* Arow = A + (size_t)(m0 + lane) * K;

    // each wave issues exactly 6 global_load_lds per stage -> vmcnt +6/stage
    auto stage = [&](int buf, int kb) {
#pragma unroll
        for (int i = 0; i < 6; i++) {
            int c = wid * 6 + i;               // 0..23 wave-uniform
            if (c < 8) {
                __builtin_amdgcn_global_load_lds(
                    (const __attribute__((address_space(1))) void*)(Arow + kb + c * 8),
                    (__attribute__((address_space(3))) void*)(&As[buf][c][0][0]), 16, 0, 0);
            } else {
                int idx = c - 8, kgc = idx & 7, rh = idx >> 3;
                __builtin_amdgcn_global_load_lds(
                    (const __attribute__((address_space(1))) void*)
                        (W + (size_t)(n0 + rh * 64 + lane) * K + kb + kgc * 8),
                    (__attribute__((address_space(3))) void*)(&Ws[buf][kgc][rh * 64][0]),
                    16, 0, 0);
            }
        }
    };

    stage(0, k0);
    stage(1, k0 + 64);
    stage(2, k0 + 128);

    int cur = 0;
    for (int tt = 0; tt < nsteps; ++tt) {
        int rem = nsteps - 1 - tt;
        // drain exactly the oldest stage; keep up to 2 stages in flight
        if (rem >= 2)      asm volatile("s_waitcnt vmcnt(12)" ::: "memory");
        else if (rem == 1) asm volatile("s_waitcnt vmcnt(6)"  ::: "memory");
        else               asm volatile("s_waitcnt vmcnt(0)"  ::: "memory");
        __builtin_amdgcn_s_barrier();
        asm volatile("" ::: "memory");
#pragma unroll
        for (int h = 0; h < 2; h++) {
            bf16x8 av[2], bv[4];
#pragma unroll
            for (int f = 0; f < 2; f++)
                av[f] = *(const bf16x8*)(&As[cur][h * 4 + kg][wm + f * 16 + fr][0]);
#pragma unroll
            for (int f = 0; f < 4; f++)
                bv[f] = *(const bf16x8*)(&Ws[cur][h * 4 + kg][wn + f * 16 + fr][0]);
#pragma unroll
            for (int fm = 0; fm < 2; fm++)
#pragma unroll
                for (int fn = 0; fn < 4; fn++)
                    acc[fm][fn] = __builtin_amdgcn_mfma_f32_16x16x32_bf16(
                        av[fm], bv[fn], acc[fm][fn], 0, 0, 0);
        }
        asm volatile("" ::: "memory");
        __builtin_amdgcn_s_barrier();          // all waves done reading buf cur
        asm volatile("" ::: "memory");
        if (tt + 3 < nsteps) stage(cur, k0 + (tt + 3) * 64);   // overwrite cur
        cur = (cur == 2) ? 0 : cur + 1;
    }

    float* Cout = Cp + (size_t)bz * ((size_t)M * N);
    int row = m0 + wm + (lane >> 4) * 4;
    int col = n0 + wn + fr;
#pragma unroll
    for (int fm = 0; fm < 2; fm++)
#pragma unroll
        for (int fn = 0; fn < 4; fn++)
#pragma unroll
            for (int r = 0; r < 4; r++)
                Cout[(size_t)(row + fm * 16 + r) * N + col + fn * 16] = acc[fm][fn][r];
}

// ---------------------------------------------------------------------------
// sum ks partial slices + bias + relu -> bf16  (N == HIDN)
__global__ __launch_bounds__(256) void fc_ep_k(const float* __restrict__ Cp,
                                               const float* __restrict__ bias,
                                               unsigned short* __restrict__ dst,
                                               int MN, int ks) {
    int i = blockIdx.x * 256 + threadIdx.x;
    if (i >= MN) return;
    float s = 0.f;
    for (int p = 0; p < ks; p++) s += Cp[(size_t)p * MN + i];
    s = fmaxf(s + bias[i & (HIDN - 1)], 0.f);
    dst[i] = f2bf(s);
}

// head accumulator (512x512) -> bias + reg out + softmax(cls) out. Block = roi.
__global__ void head_ep_k(const float* __restrict__ hf,
                          const float* __restrict__ bc,
                          const float* __restrict__ br,
                          float* __restrict__ out) {
    int r = blockIdx.x, l = threadIdx.x;   // 64 threads
    const float* row = hf + (size_t)r * NHEAD;

    float* reg = out + OUT_ROIS + OUT_CLS + (size_t)r * NREG;
    for (int j = l; j < NREG; j += 64) reg[j] = row[NCLS + j] + br[j];

    float v0 = row[l] + bc[l];
    float v1 = (l + 64 < NCLS) ? row[l + 64] + bc[l + 64] : -INFINITY;
    float m = fmaxf(v0, v1);
#pragma unroll
    for (int o = 32; o; o >>= 1) m = fmaxf(m, __shfl_xor(m, o));
    float e0 = __expf(v0 - m);
    float e1 = (l + 64 < NCLS) ? __expf(v1 - m) : 0.f;
    float s = e0 + e1;
#pragma unroll
    for (int o = 32; o; o >>= 1) s += __shfl_xor(s, o);
    float inv = 1.f / s;
    float* cls = out + OUT_ROIS + (size_t)r * NCLS;
    cls[l] = e0 * inv;
    if (l + 64 < NCLS) cls[l + 64] = e1 * inv;
}

// ---------------------------------------------------------------------------
extern "C" void kernel_launch(void* const* d_in, const int* in_sizes, int n_in,
                              void* d_out, int out_size, void* d_ws, size_t ws_size,
                              hipStream_t stream) {
    const float* p2   = (const float*)d_in[0];
    const float* p3   = (const float*)d_in[1];
    const float* p4   = (const float*)d_in[2];
    const float* p5   = (const float*)d_in[3];
    const float* rois = (const float*)d_in[4];
    const float* w1   = (const float*)d_in[5];
    const float* b1   = (const float*)d_in[6];
    const float* w2   = (const float*)d_in[7];
    const float* b2   = (const float*)d_in[8];
    const float* wc   = (const float*)d_in[9];
    const float* bc   = (const float*)d_in[10];
    const float* wr   = (const float*)d_in[11];
    const float* br   = (const float*)d_in[12];

    float* out = (float*)d_out;

    const int KS1 = 14;   // FC1 split-K (12544 = 14 * 896)

    // workspace carve-up (256B-aligned chunks)
    char* p = (char*)d_ws;
    auto alloc = [&](size_t bytes) { char* r = p; p += (bytes + 255) & ~(size_t)255; return r; };
    unsigned short* xpool = (unsigned short*)alloc((size_t)NROI * DDIM * 2);    // 12.8 MB
    unsigned short* y1b   = (unsigned short*)alloc((size_t)NROI * HIDN * 2);
    unsigned short* y2b   = (unsigned short*)alloc((size_t)NROI * HIDN * 2);
    unsigned short* w1b   = (unsigned short*)alloc((size_t)HIDN * DDIM * 2);    // 25.7 MB
    unsigned short* w2b   = (unsigned short*)alloc((size_t)HIDN * HIDN * 2);
    unsigned short* whd   = (unsigned short*)alloc((size_t)NHEAD * HIDN * 2);
    float*          hf    = (float*)alloc((size_t)NROI * NHEAD * 4);            // 1 MB
    unsigned short* ft0 = (unsigned short*)alloc((size_t)2 * 40000 * CCH * 2);  // 41 MB
    unsigned short* ft1 = (unsigned short*)alloc((size_t)2 * 10000 * CCH * 2);
    unsigned short* ft2 = (unsigned short*)alloc((size_t)2 * 2500 * CCH * 2);
    unsigned short* ft3 = (unsigned short*)alloc((size_t)2 * 625 * CCH * 2);
    bool nhwc = (size_t)(p - (char*)d_ws) <= ws_size;

    // FC1 partials alias ft0 (features dead after roi_align; same-stream order;
    // transpose fully rewrites ft0 before roi_align each call). 29.4 <= 41 MB.
    float* part = (float*)ft0;

    prep_k<<<PS_B4, 256, 0, stream>>>(rois, w1, w2, wc, wr, out, hf, w1b, w2b, whd);

    if (nhwc) {
        transpose_k<<<dim3(417, 4, 2), 256, 0, stream>>>(p2, p3, p4, p5,
                                                         ft0, ft1, ft2, ft3);
        roi_align_k<<<dim3(POOLP, NROI), 256, 0, stream>>>(ft0, ft1, ft2, ft3, rois, xpool);
    } else {
        roi_align_nchw_k<<<dim3(POOLP, NROI), 256, 0, stream>>>(p2, p3, p4, p5, rois, xpool);
    }

    // FC1: (512,12544)x(1024,12544)^T, 64x128 tile, split-K 14 partials,
    // counted-vmcnt depth-2 pipeline
    gemm128_bf16_k<<<8 * 8 * KS1, 256, 0, stream>>>(
        xpool, w1b, part, NROI, HIDN, DDIM, DDIM / KS1);
    fc_ep_k<<<(NROI * HIDN + 255) / 256, 256, 0, stream>>>(part, b1, y1b, NROI * HIDN, KS1);

    // FC2: (512,1024)x(1024,1024)^T, single-K, fused bias+relu epilogue
    gemm_fc2_k<<<dim3(HIDN / 64, NROI / 64), 256, 0, stream>>>(
        y1b, w2b, b2, y2b, NROI, HIDN, HIDN);

    // head: (512,1024)x(512,1024)^T, split-K 4, atomic acc
    gemm_bf16_k<<<dim3(NHEAD / 64, NROI / 64, 4), 256, 0, stream>>>(
        y2b, whd, hf, NROI, NHEAD, HIDN, HIDN / 4);
    head_ep_k<<<NROI, 64, 0, stream>>>(hf, bc, br, out);
}

// Round 12
// 167.712 us; speedup vs baseline: 1.0796x; 1.0796x over previous
//
#include <hip/hip_runtime.h>
#include <hip/hip_bf16.h>
#include <math.h>

// Problem constants
#define NROI   512
#define CCH    256
#define POOLP  7
#define DDIM   12544   // 256*7*7
#define HIDN   1024
#define NCLS   81
#define NREG   324
#define NHEAD  512           // padded head N: 81 cls + 324 reg + 107 pad
#define OUT_ROIS   2560      // 2*256*5
#define OUT_CLS    (512*81)

typedef __attribute__((ext_vector_type(4))) float f32x4;
typedef __attribute__((ext_vector_type(8))) short bf16x8;

static __device__ __forceinline__ unsigned short f2bf(float x) {
    __hip_bfloat16 h = __float2bfloat16(x);
    return *reinterpret_cast<unsigned short*>(&h);
}
static __device__ __forceinline__ float bf2f(unsigned short u) {
    unsigned int b = ((unsigned int)u) << 16;
    return *reinterpret_cast<float*>(&b);
}

// ---------------------------------------------------------------------------
// prep: [0,10) rois | [10,266) zero hf (1MB) | [266,1290) w2 cvt
//       | [1290,2314) head pack | [2314,3338) w1 permute
#define PS_B0 10
#define PS_B1 (PS_B0 + 256)
#define PS_B2 (PS_B1 + 1024)
#define PS_B3 (PS_B2 + 1024)
#define PS_B4 (PS_B3 + 1024)
__global__ __launch_bounds__(256) void prep_k(const float* __restrict__ rois,
                                              const float* __restrict__ w1,
                                              const float* __restrict__ w2,
                                              const float* __restrict__ wc,
                                              const float* __restrict__ wr,
                                              float* __restrict__ out,
                                              float* __restrict__ hf,
                                              unsigned short* __restrict__ w1b,
                                              unsigned short* __restrict__ w2b,
                                              unsigned short* __restrict__ whd) {
    __shared__ unsigned short lw[49 * 258];   // used by permute range only
    int bid = blockIdx.x, t = threadIdx.x;
    if (bid < PS_B0) {
        int i = bid * 256 + t;
        if (i < OUT_ROIS) out[i] = rois[i];
    } else if (bid < PS_B1) {
        int i = (bid - PS_B0) * 256 + t;              // float4, 65536 total
        ((float4*)hf)[i] = make_float4(0.f, 0.f, 0.f, 0.f);
    } else if (bid < PS_B2) {
        int i = (bid - PS_B1) * 256 + t;              // float4, 262144 total
        float4 v = ((const float4*)w2)[i];
        ushort4 o;
        o.x = f2bf(v.x); o.y = f2bf(v.y); o.z = f2bf(v.z); o.w = f2bf(v.w);
        ((ushort4*)w2b)[i] = o;
    } else if (bid < PS_B3) {
        int i2 = (bid - PS_B2) * 256 + t;             // ushort2, 262144 total
        int r = i2 >> 9, c = (i2 & 511) << 1;
        float v0, v1;
        if (r < NCLS)             { v0 = wc[r * HIDN + c]; v1 = wc[r * HIDN + c + 1]; }
        else if (r < NCLS + NREG) { v0 = wr[(r - NCLS) * HIDN + c]; v1 = wr[(r - NCLS) * HIDN + c + 1]; }
        else                      { v0 = 0.f; v1 = 0.f; }
        ((unsigned int*)whd)[i2] = (unsigned int)f2bf(v0) | ((unsigned int)f2bf(v1) << 16);
    } else {
        // w1 permute: w1b[n][s*256+c] = w1[n][c*49+s]
        int n = bid - PS_B3;
        const float* src = w1 + (size_t)n * DDIM;
        for (int k = t; k < DDIM; k += 256) {
            int c = k / 49;
            int s = k - c * 49;
            lw[s * 258 + c] = f2bf(src[k]);
        }
        __syncthreads();
        unsigned int* dst = (unsigned int*)(w1b + (size_t)n * DDIM);
        for (int j2 = t; j2 < DDIM / 2; j2 += 256) {
            int s = j2 >> 7, c2 = (j2 & 127) << 1;
            dst[j2] = lw[s * 258 + c2] | ((unsigned int)lw[s * 258 + c2 + 1] << 16);
        }
    }
}

// ---------------------------------------------------------------------------
// NCHW fp32 -> NHWC bf16 transpose v5: tile 128 s x 64 c, bf16 LDS 16.9 KB
// (8 blocks/CU) + 512B read segments + XOR-swizzled LDS (conflict-free).
// x: [0,313) p2 | [313,392) p3 | [392,412) p4 | [412,417) p5 ; y: c-tile ; z: b
__global__ __launch_bounds__(256) void transpose_k(const float* __restrict__ p2,
                                                   const float* __restrict__ p3,
                                                   const float* __restrict__ p4,
                                                   const float* __restrict__ p5,
                                                   unsigned short* __restrict__ f0,
                                                   unsigned short* __restrict__ f1,
                                                   unsigned short* __restrict__ f2,
                                                   unsigned short* __restrict__ f3) {
    __shared__ unsigned short sm[128][66];
    int idx = blockIdx.x;
    const float* in; unsigned short* op; int S, base;
    if (idx < 313)      { in = p2; op = f0; S = 40000; base = 0; }
    else if (idx < 392) { in = p3; op = f1; S = 10000; base = 313; }
    else if (idx < 412) { in = p4; op = f2; S = 2500;  base = 392; }
    else                { in = p5; op = f3; S = 625;   base = 412; }
    int s0 = (idx - base) * 128;
    int c0 = blockIdx.y * 64;
    int b  = blockIdx.z;
    int t  = threadIdx.x;

    int k = t & 31, g = t >> 5;
    bool vec = (s0 + 128 <= S);
#pragma unroll
    for (int jj = 0; jj < 8; jj++) {
        int c = g + jj * 8;
        const float* src = in + ((size_t)(b * CCH + c0 + c)) * S + s0 + k * 4;
        if (vec) {
            float4 v = *(const float4*)src;
#pragma unroll
            for (int e = 0; e < 4; e++) {
                int s = k * 4 + e;
                float val = (e == 0) ? v.x : (e == 1) ? v.y : (e == 2) ? v.z : v.w;
                sm[s][c ^ ((s & 7) << 3)] = f2bf(val);
            }
        } else {
#pragma unroll
            for (int e = 0; e < 4; e++) {
                int s = k * 4 + e;
                sm[s][c ^ ((s & 7) << 3)] =
                    (s0 + s < S) ? f2bf(src[e]) : (unsigned short)0;
            }
        }
    }
    __syncthreads();

    int lane = t & 63, w = t >> 6;
    int rl = lane >> 4, cw = (lane & 15) * 4;
#pragma unroll
    for (int i = 0; i < 8; i++) {
        int s = w * 32 + i * 4 + rl;
        if (s0 + s < S) {
            int sw = (s & 7) << 3;
            unsigned short u0 = sm[s][(cw + 0) ^ sw];
            unsigned short u1 = sm[s][(cw + 1) ^ sw];
            unsigned short u2 = sm[s][(cw + 2) ^ sw];
            unsigned short u3 = sm[s][(cw + 3) ^ sw];
            uint2 v;
            v.x = (unsigned int)u0 | ((unsigned int)u1 << 16);
            v.y = (unsigned int)u2 | ((unsigned int)u3 << 16);
            *(uint2*)(op + ((size_t)b * S + s0 + s) * CCH + c0 + cw) = v;
        }
    }
}

// ---------------------------------------------------------------------------
// ROI Align, block per (py, roi), 256 threads = channels, bf16 NHWC features.
__global__ __launch_bounds__(256) void roi_align_k(const unsigned short* __restrict__ f0,
                                                   const unsigned short* __restrict__ f1,
                                                   const unsigned short* __restrict__ f2,
                                                   const unsigned short* __restrict__ f3,
                                                   const float* __restrict__ rois,
                                                   unsigned short* __restrict__ xpool) {
    __shared__ float s_f[16];
    __shared__ int   s_lo[16], s_hi[16], s_v[16];

    int py = blockIdx.x, r = blockIdx.y, t = threadIdx.x;

    float r0  = rois[r * 5 + 0];
    float rx1 = rois[r * 5 + 1], ry1 = rois[r * 5 + 2];
    float rx2 = rois[r * 5 + 3], ry2 = rois[r * 5 + 4];
    int b = (int)r0;

    float aw = rx2 - rx1 + 1.f, ah = ry2 - ry1 + 1.f;
    float lvf = floorf(log2f(sqrtf(ah * aw) / 56.f + 1e-6f));
    int lv = (int)fminf(fmaxf(lvf, 0.f), 3.f);

    const unsigned short* F = (lv == 0) ? f0 : (lv == 1) ? f1 : (lv == 2) ? f2 : f3;
    int HW      = (lv == 0) ? 200 : (lv == 1) ? 100 : (lv == 2) ? 50 : 25;
    float scale = (lv == 0) ? 0.25f : (lv == 1) ? 0.125f : (lv == 2) ? 0.0625f : 0.03125f;

    float x1 = rx1 * scale, yy1 = ry1 * scale;
    float x2 = rx2 * scale, yy2 = ry2 * scale;
    float rw = fmaxf(x2 - x1, 1.f), rh = fmaxf(yy2 - yy1, 1.f);

    if (t < 16) {
        bool isY = t < 2;
        float coord;
        if (isY) {
            float g = (float)py + ((float)t + 0.5f) * 0.5f;
            coord = yy1 + g * (rh * (1.f / 7.f));
        } else {
            int j = t - 2;
            float g = (float)(j >> 1) + ((float)(j & 1) + 0.5f) * 0.5f;
            coord = x1 + g * (rw * (1.f / 7.f));
        }
        int vld = (coord >= -1.f && coord <= (float)HW) ? 1 : 0;
        float c = fminf(fmaxf(coord, 0.f), (float)(HW - 1));
        int lo  = (int)floorf(c);
        int hi  = min(lo + 1, HW - 1);
        s_v[t] = vld; s_lo[t] = lo; s_hi[t] = hi; s_f[t] = c - (float)lo;
    }
    __syncthreads();

    const unsigned short* Fb = F + ((size_t)b * HW * HW) * CCH + t;
    size_t obase = (size_t)r * DDIM + py * 7 * 256 + t;

    for (int px = 0; px < POOLP; px++) {
        float acc = 0.f;
#pragma unroll
        for (int s = 0; s < 4; s++) {
            int iy = s >> 1;
            int ix = px * 2 + (s & 1);
            int vy = s_v[iy], vx = s_v[2 + ix];
            if (vy & vx) {
                float fy = s_f[iy], fx = s_f[2 + ix];
                int ylo = s_lo[iy], yhi = s_hi[iy];
                int xlo = s_lo[2 + ix], xhi = s_hi[2 + ix];
                float v00 = bf2f(Fb[((size_t)ylo * HW + xlo) * CCH]);
                float v01 = bf2f(Fb[((size_t)ylo * HW + xhi) * CCH]);
                float v10 = bf2f(Fb[((size_t)yhi * HW + xlo) * CCH]);
                float v11 = bf2f(Fb[((size_t)yhi * HW + xhi) * CCH]);
                acc += (1.f - fy) * ((1.f - fx) * v00 + fx * v01)
                     + fy * ((1.f - fx) * v10 + fx * v11);
            }
        }
        xpool[obase + px * 256] = f2bf(acc * 0.25f);
    }
}

// NCHW fp32 fallback (only if ws too small for NHWC staging)
__global__ __launch_bounds__(256) void roi_align_nchw_k(const float* __restrict__ f0,
                                                        const float* __restrict__ f1,
                                                        const float* __restrict__ f2,
                                                        const float* __restrict__ f3,
                                                        const float* __restrict__ rois,
                                                        unsigned short* __restrict__ xpool) {
    __shared__ float s_f[16];
    __shared__ int   s_lo[16], s_hi[16], s_v[16];
    int py = blockIdx.x, r = blockIdx.y, t = threadIdx.x;
    float r0  = rois[r * 5 + 0];
    float rx1 = rois[r * 5 + 1], ry1 = rois[r * 5 + 2];
    float rx2 = rois[r * 5 + 3], ry2 = rois[r * 5 + 4];
    int b = (int)r0;
    float aw = rx2 - rx1 + 1.f, ah = ry2 - ry1 + 1.f;
    float lvf = floorf(log2f(sqrtf(ah * aw) / 56.f + 1e-6f));
    int lv = (int)fminf(fmaxf(lvf, 0.f), 3.f);
    const float* F = (lv == 0) ? f0 : (lv == 1) ? f1 : (lv == 2) ? f2 : f3;
    int HW      = (lv == 0) ? 200 : (lv == 1) ? 100 : (lv == 2) ? 50 : 25;
    float scale = (lv == 0) ? 0.25f : (lv == 1) ? 0.125f : (lv == 2) ? 0.0625f : 0.03125f;
    float x1 = rx1 * scale, yy1 = ry1 * scale;
    float x2 = rx2 * scale, yy2 = ry2 * scale;
    float rw = fmaxf(x2 - x1, 1.f), rh = fmaxf(yy2 - yy1, 1.f);
    if (t < 16) {
        bool isY = t < 2;
        float coord;
        if (isY) {
            float g = (float)py + ((float)t + 0.5f) * 0.5f;
            coord = yy1 + g * (rh * (1.f / 7.f));
        } else {
            int j = t - 2;
            float g = (float)(j >> 1) + ((float)(j & 1) + 0.5f) * 0.5f;
            coord = x1 + g * (rw * (1.f / 7.f));
        }
        int vld = (coord >= -1.f && coord <= (float)HW) ? 1 : 0;
        float c = fminf(fmaxf(coord, 0.f), (float)(HW - 1));
        int lo  = (int)floorf(c);
        int hi  = min(lo + 1, HW - 1);
        s_v[t] = vld; s_lo[t] = lo; s_hi[t] = hi; s_f[t] = c - (float)lo;
    }
    __syncthreads();
    const float* Fb = F + ((size_t)b * CCH + t) * HW * HW;
    size_t obase = (size_t)r * DDIM + py * 7 * 256 + t;
    for (int px = 0; px < POOLP; px++) {
        float acc = 0.f;
#pragma unroll
        for (int s = 0; s < 4; s++) {
            int iy = s >> 1, ix = px * 2 + (s & 1);
            int vy = s_v[iy], vx = s_v[2 + ix];
            if (vy & vx) {
                float fy = s_f[iy], fx = s_f[2 + ix];
                int ylo = s_lo[iy], yhi = s_hi[iy];
                int xlo = s_lo[2 + ix], xhi = s_hi[2 + ix];
                float v00 = Fb[(size_t)ylo * HW + xlo];
                float v01 = Fb[(size_t)ylo * HW + xhi];
                float v10 = Fb[(size_t)yhi * HW + xlo];
                float v11 = Fb[(size_t)yhi * HW + xhi];
                acc += (1.f - fy) * ((1.f - fx) * v00 + fx * v01)
                     + fy * ((1.f - fx) * v10 + fx * v11);
            }
        }
        xpool[obase + px * 256] = f2bf(acc * 0.25f);
    }
}

// ---------------------------------------------------------------------------
// 64x64 bf16 MFMA GEMM, double-buffered, atomic split-K (head).
__global__ __launch_bounds__(256) void gemm_bf16_k(const unsigned short* __restrict__ A,
                                                   const unsigned short* __restrict__ W,
                                                   float* __restrict__ Cacc,
                                                   int M, int N, int K, int kchunk) {
    __shared__ __align__(16) unsigned short As[2][8][64][8];
    __shared__ __align__(16) unsigned short Ws[2][8][64][8];

    int t = threadIdx.x;
    int lane = t & 63, wid = t >> 6;
    int m0 = blockIdx.y * 64, n0 = blockIdx.x * 64;
    int k0 = blockIdx.z * kchunk;
    int wm = (wid >> 1) * 32, wn = (wid & 1) * 32;
    int fr = lane & 15, kg = lane >> 4;
    int nsteps = kchunk >> 6;

    f32x4 acc[2][2] = {};

    const unsigned short* Arow = A + (size_t)(m0 + lane) * K;
    const unsigned short* Wrow = W + (size_t)(n0 + lane) * K;

    auto stage = [&](int buf, int kb) {
#pragma unroll
        for (int i = 0; i < 2; i++) {
            int c = wid * 2 + i;
            __builtin_amdgcn_global_load_lds(
                (const __attribute__((address_space(1))) void*)(Arow + kb + c * 8),
                (__attribute__((address_space(3))) void*)(&As[buf][c][0][0]), 16, 0, 0);
            __builtin_amdgcn_global_load_lds(
                (const __attribute__((address_space(1))) void*)(Wrow + kb + c * 8),
                (__attribute__((address_space(3))) void*)(&Ws[buf][c][0][0]), 16, 0, 0);
        }
    };

    stage(0, k0);
    __syncthreads();
    int cur = 0;
    for (int tt = 0; tt < nsteps; ++tt) {
        if (tt + 1 < nsteps) stage(cur ^ 1, k0 + (tt + 1) * 64);
#pragma unroll
        for (int h = 0; h < 2; h++) {
            bf16x8 a0 = *(const bf16x8*)(&As[cur][h * 4 + kg][wm + fr][0]);
            bf16x8 a1 = *(const bf16x8*)(&As[cur][h * 4 + kg][wm + 16 + fr][0]);
            bf16x8 b0 = *(const bf16x8*)(&Ws[cur][h * 4 + kg][wn + fr][0]);
            bf16x8 b1 = *(const bf16x8*)(&Ws[cur][h * 4 + kg][wn + 16 + fr][0]);
            acc[0][0] = __builtin_amdgcn_mfma_f32_16x16x32_bf16(a0, b0, acc[0][0], 0, 0, 0);
            acc[0][1] = __builtin_amdgcn_mfma_f32_16x16x32_bf16(a0, b1, acc[0][1], 0, 0, 0);
            acc[1][0] = __builtin_amdgcn_mfma_f32_16x16x32_bf16(a1, b0, acc[1][0], 0, 0, 0);
            acc[1][1] = __builtin_amdgcn_mfma_f32_16x16x32_bf16(a1, b1, acc[1][1], 0, 0, 0);
        }
        __syncthreads();
        cur ^= 1;
    }

    int row = m0 + wm + (lane >> 4) * 4;
    int col = n0 + wn + fr;
#pragma unroll
    for (int fm = 0; fm < 2; fm++)
#pragma unroll
        for (int fn = 0; fn < 2; fn++)
#pragma unroll
            for (int r = 0; r < 4; r++)
                atomicAdd(&Cacc[(size_t)(row + fm * 16 + r) * N + col + fn * 16],
                          acc[fm][fn][r]);
}

// ---------------------------------------------------------------------------
// FC2: single-K 64x64 GEMM with fused bias+relu+bf16 epilogue.
__global__ __launch_bounds__(256) void gemm_fc2_k(const unsigned short* __restrict__ A,
                                                  const unsigned short* __restrict__ W,
                                                  const float* __restrict__ bias,
                                                  unsigned short* __restrict__ dst,
                                                  int M, int N, int K) {
    __shared__ __align__(16) unsigned short As[2][8][64][8];
    __shared__ __align__(16) unsigned short Ws[2][8][64][8];

    int t = threadIdx.x;
    int lane = t & 63, wid = t >> 6;
    int m0 = blockIdx.y * 64, n0 = blockIdx.x * 64;
    int wm = (wid >> 1) * 32, wn = (wid & 1) * 32;
    int fr = lane & 15, kg = lane >> 4;
    int nsteps = K >> 6;

    f32x4 acc[2][2] = {};

    const unsigned short* Arow = A + (size_t)(m0 + lane) * K;
    const unsigned short* Wrow = W + (size_t)(n0 + lane) * K;

    auto stage = [&](int buf, int kb) {
#pragma unroll
        for (int i = 0; i < 2; i++) {
            int c = wid * 2 + i;
            __builtin_amdgcn_global_load_lds(
                (const __attribute__((address_space(1))) void*)(Arow + kb + c * 8),
                (__attribute__((address_space(3))) void*)(&As[buf][c][0][0]), 16, 0, 0);
            __builtin_amdgcn_global_load_lds(
                (const __attribute__((address_space(1))) void*)(Wrow + kb + c * 8),
                (__attribute__((address_space(3))) void*)(&Ws[buf][c][0][0]), 16, 0, 0);
        }
    };

    stage(0, 0);
    __syncthreads();
    int cur = 0;
    for (int tt = 0; tt < nsteps; ++tt) {
        if (tt + 1 < nsteps) stage(cur ^ 1, (tt + 1) * 64);
#pragma unroll
        for (int h = 0; h < 2; h++) {
            bf16x8 a0 = *(const bf16x8*)(&As[cur][h * 4 + kg][wm + fr][0]);
            bf16x8 a1 = *(const bf16x8*)(&As[cur][h * 4 + kg][wm + 16 + fr][0]);
            bf16x8 b0 = *(const bf16x8*)(&Ws[cur][h * 4 + kg][wn + fr][0]);
            bf16x8 b1 = *(const bf16x8*)(&Ws[cur][h * 4 + kg][wn + 16 + fr][0]);
            acc[0][0] = __builtin_amdgcn_mfma_f32_16x16x32_bf16(a0, b0, acc[0][0], 0, 0, 0);
            acc[0][1] = __builtin_amdgcn_mfma_f32_16x16x32_bf16(a0, b1, acc[0][1], 0, 0, 0);
            acc[1][0] = __builtin_amdgcn_mfma_f32_16x16x32_bf16(a1, b0, acc[1][0], 0, 0, 0);
            acc[1][1] = __builtin_amdgcn_mfma_f32_16x16x32_bf16(a1, b1, acc[1][1], 0, 0, 0);
        }
        __syncthreads();
        cur ^= 1;
    }

    int row = m0 + wm + (lane >> 4) * 4;
    int col = n0 + wn + fr;
#pragma unroll
    for (int fm = 0; fm < 2; fm++)
#pragma unroll
        for (int fn = 0; fn < 2; fn++) {
            float bv = bias[col + fn * 16];
#pragma unroll
            for (int r = 0; r < 4; r++) {
                float v = fmaxf(acc[fm][fn][r] + bv, 0.f);
                dst[(size_t)(row + fm * 16 + r) * N + col + fn * 16] = f2bf(v);
            }
        }
}

// ---------------------------------------------------------------------------
// FC1 GEMM (R3's proven structure + occupancy fix): 128x128 tile, BK=64,
// SINGLE-buffer 32KB LDS m97 2-barrier loop (5 blocks/CU by LDS), split-K 28
// PARTIALS stored as bf16 (29.4 MB), tile-major XCD swizzle: each XCD owns
// 4 consecutive tiles x 28 z -> W-panels fetched once chip-wide, A-panels 2x.
// grid = 896 linear blocks = 32 tiles x 28 z = 3.5 blocks/CU resident.
__global__ __launch_bounds__(256) void gemm128_bf16_k(const unsigned short* __restrict__ A,
                                                      const unsigned short* __restrict__ W,
                                                      unsigned short* __restrict__ Cp,
                                                      int M, int N, int K, int kchunk) {
    __shared__ __align__(16) unsigned short As[8][128][8];   // 16 KB
    __shared__ __align__(16) unsigned short Ws[8][128][8];   // 16 KB

    int lin  = blockIdx.x;
    int nb   = (lin & 7) * 112 + (lin >> 3);   // 896 = 8 XCD x 112, bijective
    int tile = nb / 28, bz = nb - tile * 28;   // z innermost per tile
    int bx = tile & 7, by = tile >> 3;

    int t = threadIdx.x;
    int lane = t & 63, wid = t >> 6;
    int m0 = by * 128, n0 = bx * 128;
    int k0 = bz * kchunk;
    int wm = (wid >> 1) * 64, wn = (wid & 1) * 64;
    int fr = lane & 15, kg = lane >> 4;

    f32x4 acc[4][4] = {};

    for (int kb = k0; kb < k0 + kchunk; kb += 64) {
#pragma unroll
        for (int i = 0; i < 4; i++) {
            int c   = wid * 4 + i;             // 0..15, wave-uniform
            int kgc = c >> 1;
            int r0w = (c & 1) * 64;
            __builtin_amdgcn_global_load_lds(
                (const __attribute__((address_space(1))) void*)
                    (A + (size_t)(m0 + r0w + lane) * K + kb + kgc * 8),
                (__attribute__((address_space(3))) void*)(&As[kgc][r0w][0]), 16, 0, 0);
            __builtin_amdgcn_global_load_lds(
                (const __attribute__((address_space(1))) void*)
                    (W + (size_t)(n0 + r0w + lane) * K + kb + kgc * 8),
                (__attribute__((address_space(3))) void*)(&Ws[kgc][r0w][0]), 16, 0, 0);
        }
        __syncthreads();
#pragma unroll
        for (int h = 0; h < 2; h++) {
            bf16x8 av[4], bv[4];
#pragma unroll
            for (int f = 0; f < 4; f++) {
                av[f] = *(const bf16x8*)(&As[h * 4 + kg][wm + f * 16 + fr][0]);
                bv[f] = *(const bf16x8*)(&Ws[h * 4 + kg][wn + f * 16 + fr][0]);
            }
#pragma unroll
            for (int fm = 0; fm < 4; fm++)
#pragma unroll
                for (int fn = 0; fn < 4; fn++)
                    acc[fm][fn] = __builtin_amdgcn_mfma_f32_16x16x32_bf16(
                        av[fm], bv[fn], acc[fm][fn], 0, 0, 0);
        }
        __syncthreads();
    }

    unsigned short* Cout = Cp + (size_t)bz * ((size_t)M * N);
    int row = m0 + wm + (lane >> 4) * 4;
    int col = n0 + wn + fr;
#pragma unroll
    for (int fm = 0; fm < 4; fm++)
#pragma unroll
        for (int fn = 0; fn < 4; fn++)
#pragma unroll
            for (int r = 0; r < 4; r++)
                Cout[(size_t)(row + fm * 16 + r) * N + col + fn * 16] =
                    f2bf(acc[fm][fn][r]);
}

// ---------------------------------------------------------------------------
// FC1 epilogue: sum 28 bf16 partial slices + bias + relu -> bf16.
// 4 elems/thread, ushort4 vector loads. MN = 512*1024.
__global__ __launch_bounds__(256) void fc_ep28_k(const unsigned short* __restrict__ Cp,
                                                 const float* __restrict__ bias,
                                                 unsigned short* __restrict__ dst,
                                                 int ks) {
    const int MN = NROI * HIDN;
    int i = blockIdx.x * 256 + threadIdx.x;        // 0 .. MN/4-1
    size_t base = (size_t)i * 4;
    float s0 = 0.f, s1 = 0.f, s2 = 0.f, s3 = 0.f;
    for (int p = 0; p < ks; p++) {
        ushort4 u = *(const ushort4*)(Cp + (size_t)p * MN + base);
        s0 += bf2f(u.x); s1 += bf2f(u.y); s2 += bf2f(u.z); s3 += bf2f(u.w);
    }
    int col = (int)(base & (HIDN - 1));
    ushort4 o;
    o.x = f2bf(fmaxf(s0 + bias[col + 0], 0.f));
    o.y = f2bf(fmaxf(s1 + bias[col + 1], 0.f));
    o.z = f2bf(fmaxf(s2 + bias[col + 2], 0.f));
    o.w = f2bf(fmaxf(s3 + bias[col + 3], 0.f));
    *(ushort4*)(dst + base) = o;
}

// head accumulator (512x512) -> bias + reg out + softmax(cls) out. Block = roi.
__global__ void head_ep_k(const float* __restrict__ hf,
                          const float* __restrict__ bc,
                          const float* __restrict__ br,
                          float* __restrict__ out) {
    int r = blockIdx.x, l = threadIdx.x;   // 64 threads
    const float* row = hf + (size_t)r * NHEAD;

    float* reg = out + OUT_ROIS + OUT_CLS + (size_t)r * NREG;
    for (int j = l; j < NREG; j += 64) reg[j] = row[NCLS + j] + br[j];

    float v0 = row[l] + bc[l];
    float v1 = (l + 64 < NCLS) ? row[l + 64] + bc[l + 64] : -INFINITY;
    float m = fmaxf(v0, v1);
#pragma unroll
    for (int o = 32; o; o >>= 1) m = fmaxf(m, __shfl_xor(m, o));
    float e0 = __expf(v0 - m);
    float e1 = (l + 64 < NCLS) ? __expf(v1 - m) : 0.f;
    float s = e0 + e1;
#pragma unroll
    for (int o = 32; o; o >>= 1) s += __shfl_xor(s, o);
    float inv = 1.f / s;
    float* cls = out + OUT_ROIS + (size_t)r * NCLS;
    cls[l] = e0 * inv;
    if (l + 64 < NCLS) cls[l + 64] = e1 * inv;
}

// ---------------------------------------------------------------------------
extern "C" void kernel_launch(void* const* d_in, const int* in_sizes, int n_in,
                              void* d_out, int out_size, void* d_ws, size_t ws_size,
                              hipStream_t stream) {
    const float* p2   = (const float*)d_in[0];
    const float* p3   = (const float*)d_in[1];
    const float* p4   = (const float*)d_in[2];
    const float* p5   = (const float*)d_in[3];
    const float* rois = (const float*)d_in[4];
    const float* w1   = (const float*)d_in[5];
    const float* b1   = (const float*)d_in[6];
    const float* w2   = (const float*)d_in[7];
    const float* b2   = (const float*)d_in[8];
    const float* wc   = (const float*)d_in[9];
    const float* bc   = (const float*)d_in[10];
    const float* wr   = (const float*)d_in[11];
    const float* br   = (const float*)d_in[12];

    float* out = (float*)d_out;

    const int KS1 = 28;   // FC1 split-K (12544 = 28 * 448)

    // workspace carve-up (256B-aligned chunks)
    char* p = (char*)d_ws;
    auto alloc = [&](size_t bytes) { char* r = p; p += (bytes + 255) & ~(size_t)255; return r; };
    unsigned short* xpool = (unsigned short*)alloc((size_t)NROI * DDIM * 2);    // 12.8 MB
    unsigned short* y1b   = (unsigned short*)alloc((size_t)NROI * HIDN * 2);
    unsigned short* y2b   = (unsigned short*)alloc((size_t)NROI * HIDN * 2);
    unsigned short* w1b   = (unsigned short*)alloc((size_t)HIDN * DDIM * 2);    // 25.7 MB
    unsigned short* w2b   = (unsigned short*)alloc((size_t)HIDN * HIDN * 2);
    unsigned short* whd   = (unsigned short*)alloc((size_t)NHEAD * HIDN * 2);
    float*          hf    = (float*)alloc((size_t)NROI * NHEAD * 4);            // 1 MB
    unsigned short* ft0 = (unsigned short*)alloc((size_t)2 * 40000 * CCH * 2);  // 41 MB
    unsigned short* ft1 = (unsigned short*)alloc((size_t)2 * 10000 * CCH * 2);
    unsigned short* ft2 = (unsigned short*)alloc((size_t)2 * 2500 * CCH * 2);
    unsigned short* ft3 = (unsigned short*)alloc((size_t)2 * 625 * CCH * 2);
    bool nhwc = (size_t)(p - (char*)d_ws) <= ws_size;

    // FC1 bf16 partials alias ft0 (features dead after roi_align; same-stream
    // order; transpose fully rewrites ft0 each call). 29.4 MB <= 41 MB.
    unsigned short* part = ft0;

    prep_k<<<PS_B4, 256, 0, stream>>>(rois, w1, w2, wc, wr, out, hf, w1b, w2b, whd);

    if (nhwc) {
        transpose_k<<<dim3(417, 4, 2), 256, 0, stream>>>(p2, p3, p4, p5,
                                                         ft0, ft1, ft2, ft3);
        roi_align_k<<<dim3(POOLP, NROI), 256, 0, stream>>>(ft0, ft1, ft2, ft3, rois, xpool);
    } else {
        roi_align_nchw_k<<<dim3(POOLP, NROI), 256, 0, stream>>>(p2, p3, p4, p5, rois, xpool);
    }

    // FC1: (512,12544)x(1024,12544)^T, 128^2 tile single-buf, split-K 28
    // bf16 partials, tile-major XCD swizzle
    gemm128_bf16_k<<<8 * 4 * KS1, 256, 0, stream>>>(
        xpool, w1b, part, NROI, HIDN, DDIM, DDIM / KS1);
    fc_ep28_k<<<(NROI * HIDN / 4 + 255) / 256, 256, 0, stream>>>(part, b1, y1b, KS1);

    // FC2: (512,1024)x(1024,1024)^T, single-K, fused bias+relu epilogue
    gemm_fc2_k<<<dim3(HIDN / 64, NROI / 64), 256, 0, stream>>>(
        y1b, w2b, b2, y2b, NROI, HIDN, HIDN);

    // head: (512,1024)x(512,1024)^T, split-K 4, atomic acc
    gemm_bf16_k<<<dim3(NHEAD / 64, NROI / 64, 4), 256, 0, stream>>>(
        y2b, whd, hf, NROI, NHEAD, HIDN, HIDN / 4);
    head_ep_k<<<NROI, 64, 0, stream>>>(hf, bc, br, out);
}

// Round 13
// 160.964 us; speedup vs baseline: 1.1249x; 1.0419x over previous
//
#include <hip/hip_runtime.h>
#include <hip/hip_bf16.h>
#include <math.h>

// Problem constants
#define NROI   512
#define CCH    256
#define POOLP  7
#define DDIM   12544   // 256*7*7
#define HIDN   1024
#define NCLS   81
#define NREG   324
#define NHEAD  512           // padded head N: 81 cls + 324 reg + 107 pad
#define OUT_ROIS   2560      // 2*256*5
#define OUT_CLS    (512*81)

typedef __attribute__((ext_vector_type(4))) float f32x4;
typedef __attribute__((ext_vector_type(8))) short bf16x8;

static __device__ __forceinline__ unsigned short f2bf(float x) {
    __hip_bfloat16 h = __float2bfloat16(x);
    return *reinterpret_cast<unsigned short*>(&h);
}
static __device__ __forceinline__ float bf2f(unsigned short u) {
    unsigned int b = ((unsigned int)u) << 16;
    return *reinterpret_cast<float*>(&b);
}

// ---------------------------------------------------------------------------
// fused preprocess: [0,ntrans) NCHW->NHWC transpose | then prep ranges:
//   +10 rois | +256 zero hf | +1024 w2 cvt | +1024 head pack | +1024 w1 permute
// ntrans = 3336 (or 0 in the no-NHWC fallback).
// LDS union: transpose 128x66 u16 = 16896 B ; w1 permute 49x130 u16 = 12740 B.
#define NTRANS 3336
__global__ __launch_bounds__(256) void fused_pre_k(
        const float* __restrict__ p2, const float* __restrict__ p3,
        const float* __restrict__ p4, const float* __restrict__ p5,
        unsigned short* __restrict__ f0, unsigned short* __restrict__ f1,
        unsigned short* __restrict__ f2, unsigned short* __restrict__ f3,
        const float* __restrict__ rois, const float* __restrict__ w1,
        const float* __restrict__ w2, const float* __restrict__ wc,
        const float* __restrict__ wr,
        float* __restrict__ out, float* __restrict__ hf,
        unsigned short* __restrict__ w1b, unsigned short* __restrict__ w2b,
        unsigned short* __restrict__ whd, int ntrans) {
    __shared__ unsigned short sm[128 * 66];    // 16.9 KB union
    int bid = blockIdx.x, t = threadIdx.x;

    if (bid < ntrans) {
        // ---- transpose v6: tile 128 s x 64 c, reg-staged 8x float4 loads,
        //      XOR-swizzled bf16 LDS, 128B-segment uint2 writes.
        int xb = bid % 417;
        int r  = bid / 417;
        int cy = r & 3, b = r >> 2;
        const float* in; unsigned short* op; int S, base;
        if (xb < 313)      { in = p2; op = f0; S = 40000; base = 0; }
        else if (xb < 392) { in = p3; op = f1; S = 10000; base = 313; }
        else if (xb < 412) { in = p4; op = f2; S = 2500;  base = 392; }
        else               { in = p5; op = f3; S = 625;   base = 412; }
        int s0 = (xb - base) * 128;
        int c0 = cy * 64;

        int k = t & 31, g = t >> 5;
        bool vec = (s0 + 128 <= S);
        if (vec) {
            float4 vv[8];
            const float* srcb = in + ((size_t)(b * CCH + c0 + g)) * S + s0 + k * 4;
#pragma unroll
            for (int jj = 0; jj < 8; jj++)
                vv[jj] = *(const float4*)(srcb + (size_t)jj * 8 * S);
#pragma unroll
            for (int jj = 0; jj < 8; jj++) {
                int c = g + jj * 8;
                int s = k * 4;
                sm[(s + 0) * 66 + (c ^ (((s + 0) & 7) << 3))] = f2bf(vv[jj].x);
                sm[(s + 1) * 66 + (c ^ (((s + 1) & 7) << 3))] = f2bf(vv[jj].y);
                sm[(s + 2) * 66 + (c ^ (((s + 2) & 7) << 3))] = f2bf(vv[jj].z);
                sm[(s + 3) * 66 + (c ^ (((s + 3) & 7) << 3))] = f2bf(vv[jj].w);
            }
        } else {
#pragma unroll
            for (int jj = 0; jj < 8; jj++) {
                int c = g + jj * 8;
                const float* src = in + ((size_t)(b * CCH + c0 + c)) * S + s0 + k * 4;
#pragma unroll
                for (int e = 0; e < 4; e++) {
                    int s = k * 4 + e;
                    sm[s * 66 + (c ^ ((s & 7) << 3))] =
                        (s0 + s < S) ? f2bf(src[e]) : (unsigned short)0;
                }
            }
        }
        __syncthreads();

        int lane = t & 63, w = t >> 6;
        int rl = lane >> 4, cw = (lane & 15) * 4;
#pragma unroll
        for (int i = 0; i < 8; i++) {
            int s = w * 32 + i * 4 + rl;
            if (s0 + s < S) {
                int sw = (s & 7) << 3;
                unsigned short u0 = sm[s * 66 + ((cw + 0) ^ sw)];
                unsigned short u1 = sm[s * 66 + ((cw + 1) ^ sw)];
                unsigned short u2 = sm[s * 66 + ((cw + 2) ^ sw)];
                unsigned short u3 = sm[s * 66 + ((cw + 3) ^ sw)];
                uint2 v;
                v.x = (unsigned int)u0 | ((unsigned int)u1 << 16);
                v.y = (unsigned int)u2 | ((unsigned int)u3 << 16);
                *(uint2*)(op + ((size_t)b * S + s0 + s) * CCH + c0 + cw) = v;
            }
        }
        return;
    }

    int pb = bid - ntrans;
    if (pb < 10) {
        int i = pb * 256 + t;
        if (i < OUT_ROIS) out[i] = rois[i];
    } else if (pb < 10 + 256) {
        int i = (pb - 10) * 256 + t;                  // float4, 65536 total
        ((float4*)hf)[i] = make_float4(0.f, 0.f, 0.f, 0.f);
    } else if (pb < 10 + 256 + 1024) {
        int i = (pb - 266) * 256 + t;                 // float4, 262144 total
        float4 v = ((const float4*)w2)[i];
        ushort4 o;
        o.x = f2bf(v.x); o.y = f2bf(v.y); o.z = f2bf(v.z); o.w = f2bf(v.w);
        ((ushort4*)w2b)[i] = o;
    } else if (pb < 10 + 256 + 2048) {
        int i2 = (pb - 1290) * 256 + t;               // ushort2, 262144 total
        int r = i2 >> 9, c = (i2 & 511) << 1;
        float v0, v1;
        if (r < NCLS)             { v0 = wc[r * HIDN + c]; v1 = wc[r * HIDN + c + 1]; }
        else if (r < NCLS + NREG) { v0 = wr[(r - NCLS) * HIDN + c]; v1 = wr[(r - NCLS) * HIDN + c + 1]; }
        else                      { v0 = 0.f; v1 = 0.f; }
        ((unsigned int*)whd)[i2] = (unsigned int)f2bf(v0) | ((unsigned int)f2bf(v1) << 16);
    } else {
        // w1 permute, two 128-channel passes in 49x130 LDS (12.7 KB):
        // w1b[n][s*256+c] = w1[n][c*49+s]
        int n = pb - (10 + 256 + 2048);
        const float* src = w1 + (size_t)n * DDIM;
        unsigned int* drow = (unsigned int*)(w1b + (size_t)n * DDIM);
#pragma unroll
        for (int h = 0; h < 2; h++) {
            int kbase = h * 128 * 49;                 // 6272 per half
            for (int k = t; k < 128 * 49; k += 256) {
                int kk = kbase + k;
                int c  = kk / 49;                     // global channel
                int s  = kk - c * 49;
                sm[s * 130 + (c - h * 128)] = f2bf(src[kk]);
            }
            __syncthreads();
            for (int j2 = t; j2 < 49 * 64; j2 += 256) {
                int s = j2 >> 6, q = j2 & 63;
                unsigned int v = sm[s * 130 + q * 2]
                               | ((unsigned int)sm[s * 130 + q * 2 + 1] << 16);
                drow[s * 128 + h * 64 + q] = v;
            }
            __syncthreads();
        }
    }
}

// ---------------------------------------------------------------------------
// ROI Align, block per (py, roi), 256 threads = channels, bf16 NHWC features.
__global__ __launch_bounds__(256) void roi_align_k(const unsigned short* __restrict__ f0,
                                                   const unsigned short* __restrict__ f1,
                                                   const unsigned short* __restrict__ f2,
                                                   const unsigned short* __restrict__ f3,
                                                   const float* __restrict__ rois,
                                                   unsigned short* __restrict__ xpool) {
    __shared__ float s_f[16];
    __shared__ int   s_lo[16], s_hi[16], s_v[16];

    int py = blockIdx.x, r = blockIdx.y, t = threadIdx.x;

    float r0  = rois[r * 5 + 0];
    float rx1 = rois[r * 5 + 1], ry1 = rois[r * 5 + 2];
    float rx2 = rois[r * 5 + 3], ry2 = rois[r * 5 + 4];
    int b = (int)r0;

    float aw = rx2 - rx1 + 1.f, ah = ry2 - ry1 + 1.f;
    float lvf = floorf(log2f(sqrtf(ah * aw) / 56.f + 1e-6f));
    int lv = (int)fminf(fmaxf(lvf, 0.f), 3.f);

    const unsigned short* F = (lv == 0) ? f0 : (lv == 1) ? f1 : (lv == 2) ? f2 : f3;
    int HW      = (lv == 0) ? 200 : (lv == 1) ? 100 : (lv == 2) ? 50 : 25;
    float scale = (lv == 0) ? 0.25f : (lv == 1) ? 0.125f : (lv == 2) ? 0.0625f : 0.03125f;

    float x1 = rx1 * scale, yy1 = ry1 * scale;
    float x2 = rx2 * scale, yy2 = ry2 * scale;
    float rw = fmaxf(x2 - x1, 1.f), rh = fmaxf(yy2 - yy1, 1.f);

    if (t < 16) {
        bool isY = t < 2;
        float coord;
        if (isY) {
            float g = (float)py + ((float)t + 0.5f) * 0.5f;
            coord = yy1 + g * (rh * (1.f / 7.f));
        } else {
            int j = t - 2;
            float g = (float)(j >> 1) + ((float)(j & 1) + 0.5f) * 0.5f;
            coord = x1 + g * (rw * (1.f / 7.f));
        }
        int vld = (coord >= -1.f && coord <= (float)HW) ? 1 : 0;
        float c = fminf(fmaxf(coord, 0.f), (float)(HW - 1));
        int lo  = (int)floorf(c);
        int hi  = min(lo + 1, HW - 1);
        s_v[t] = vld; s_lo[t] = lo; s_hi[t] = hi; s_f[t] = c - (float)lo;
    }
    __syncthreads();

    const unsigned short* Fb = F + ((size_t)b * HW * HW) * CCH + t;
    size_t obase = (size_t)r * DDIM + py * 7 * 256 + t;

    for (int px = 0; px < POOLP; px++) {
        float acc = 0.f;
#pragma unroll
        for (int s = 0; s < 4; s++) {
            int iy = s >> 1;
            int ix = px * 2 + (s & 1);
            int vy = s_v[iy], vx = s_v[2 + ix];
            if (vy & vx) {
                float fy = s_f[iy], fx = s_f[2 + ix];
                int ylo = s_lo[iy], yhi = s_hi[iy];
                int xlo = s_lo[2 + ix], xhi = s_hi[2 + ix];
                float v00 = bf2f(Fb[((size_t)ylo * HW + xlo) * CCH]);
                float v01 = bf2f(Fb[((size_t)ylo * HW + xhi) * CCH]);
                float v10 = bf2f(Fb[((size_t)yhi * HW + xlo) * CCH]);
                float v11 = bf2f(Fb[((size_t)yhi * HW + xhi) * CCH]);
                acc += (1.f - fy) * ((1.f - fx) * v00 + fx * v01)
                     + fy * ((1.f - fx) * v10 + fx * v11);
            }
        }
        xpool[obase + px * 256] = f2bf(acc * 0.25f);
    }
}

// NCHW fp32 fallback (only if ws too small for NHWC staging)
__global__ __launch_bounds__(256) void roi_align_nchw_k(const float* __restrict__ f0,
                                                        const float* __restrict__ f1,
                                                        const float* __restrict__ f2,
                                                        const float* __restrict__ f3,
                                                        const float* __restrict__ rois,
                                                        unsigned short* __restrict__ xpool) {
    __shared__ float s_f[16];
    __shared__ int   s_lo[16], s_hi[16], s_v[16];
    int py = blockIdx.x, r = blockIdx.y, t = threadIdx.x;
    float r0  = rois[r * 5 + 0];
    float rx1 = rois[r * 5 + 1], ry1 = rois[r * 5 + 2];
    float rx2 = rois[r * 5 + 3], ry2 = rois[r * 5 + 4];
    int b = (int)r0;
    float aw = rx2 - rx1 + 1.f, ah = ry2 - ry1 + 1.f;
    float lvf = floorf(log2f(sqrtf(ah * aw) / 56.f + 1e-6f));
    int lv = (int)fminf(fmaxf(lvf, 0.f), 3.f);
    const float* F = (lv == 0) ? f0 : (lv == 1) ? f1 : (lv == 2) ? f2 : f3;
    int HW      = (lv == 0) ? 200 : (lv == 1) ? 100 : (lv == 2) ? 50 : 25;
    float scale = (lv == 0) ? 0.25f : (lv == 1) ? 0.125f : (lv == 2) ? 0.0625f : 0.03125f;
    float x1 = rx1 * scale, yy1 = ry1 * scale;
    float x2 = rx2 * scale, yy2 = ry2 * scale;
    float rw = fmaxf(x2 - x1, 1.f), rh = fmaxf(yy2 - yy1, 1.f);
    if (t < 16) {
        bool isY = t < 2;
        float coord;
        if (isY) {
            float g = (float)py + ((float)t + 0.5f) * 0.5f;
            coord = yy1 + g * (rh * (1.f / 7.f));
        } else {
            int j = t - 2;
            float g = (float)(j >> 1) + ((float)(j & 1) + 0.5f) * 0.5f;
            coord = x1 + g * (rw * (1.f / 7.f));
        }
        int vld = (coord >= -1.f && coord <= (float)HW) ? 1 : 0;
        float c = fminf(fmaxf(coord, 0.f), (float)(HW - 1));
        int lo  = (int)floorf(c);
        int hi  = min(lo + 1, HW - 1);
        s_v[t] = vld; s_lo[t] = lo; s_hi[t] = hi; s_f[t] = c - (float)lo;
    }
    __syncthreads();
    const float* Fb = F + ((size_t)b * CCH + t) * HW * HW;
    size_t obase = (size_t)r * DDIM + py * 7 * 256 + t;
    for (int px = 0; px < POOLP; px++) {
        float acc = 0.f;
#pragma unroll
        for (int s = 0; s < 4; s++) {
            int iy = s >> 1, ix = px * 2 + (s & 1);
            int vy = s_v[iy], vx = s_v[2 + ix];
            if (vy & vx) {
                float fy = s_f[iy], fx = s_f[2 + ix];
                int ylo = s_lo[iy], yhi = s_hi[iy];
                int xlo = s_lo[2 + ix], xhi = s_hi[2 + ix];
                float v00 = Fb[(size_t)ylo * HW + xlo];
                float v01 = Fb[(size_t)ylo * HW + xhi];
                float v10 = Fb[(size_t)yhi * HW + xlo];
                float v11 = Fb[(size_t)yhi * HW + xhi];
                acc += (1.f - fy) * ((1.f - fx) * v00 + fx * v01)
                     + fy * ((1.f - fx) * v10 + fx * v11);
            }
        }
        xpool[obase + px * 256] = f2bf(acc * 0.25f);
    }
}

// ---------------------------------------------------------------------------
// 64x64 bf16 MFMA GEMM, double-buffered, atomic split-K (head).
__global__ __launch_bounds__(256) void gemm_bf16_k(const unsigned short* __restrict__ A,
                                                   const unsigned short* __restrict__ W,
                                                   float* __restrict__ Cacc,
                                                   int M, int N, int K, int kchunk) {
    __shared__ __align__(16) unsigned short As[2][8][64][8];
    __shared__ __align__(16) unsigned short Ws[2][8][64][8];

    int t = threadIdx.x;
    int lane = t & 63, wid = t >> 6;
    int m0 = blockIdx.y * 64, n0 = blockIdx.x * 64;
    int k0 = blockIdx.z * kchunk;
    int wm = (wid >> 1) * 32, wn = (wid & 1) * 32;
    int fr = lane & 15, kg = lane >> 4;
    int nsteps = kchunk >> 6;

    f32x4 acc[2][2] = {};

    const unsigned short* Arow = A + (size_t)(m0 + lane) * K;
    const unsigned short* Wrow = W + (size_t)(n0 + lane) * K;

    auto stage = [&](int buf, int kb) {
#pragma unroll
        for (int i = 0; i < 2; i++) {
            int c = wid * 2 + i;
            __builtin_amdgcn_global_load_lds(
                (const __attribute__((address_space(1))) void*)(Arow + kb + c * 8),
                (__attribute__((address_space(3))) void*)(&As[buf][c][0][0]), 16, 0, 0);
            __builtin_amdgcn_global_load_lds(
                (const __attribute__((address_space(1))) void*)(Wrow + kb + c * 8),
                (__attribute__((address_space(3))) void*)(&Ws[buf][c][0][0]), 16, 0, 0);
        }
    };

    stage(0, k0);
    __syncthreads();
    int cur = 0;
    for (int tt = 0; tt < nsteps; ++tt) {
        if (tt + 1 < nsteps) stage(cur ^ 1, k0 + (tt + 1) * 64);
#pragma unroll
        for (int h = 0; h < 2; h++) {
            bf16x8 a0 = *(const bf16x8*)(&As[cur][h * 4 + kg][wm + fr][0]);
            bf16x8 a1 = *(const bf16x8*)(&As[cur][h * 4 + kg][wm + 16 + fr][0]);
            bf16x8 b0 = *(const bf16x8*)(&Ws[cur][h * 4 + kg][wn + fr][0]);
            bf16x8 b1 = *(const bf16x8*)(&Ws[cur][h * 4 + kg][wn + 16 + fr][0]);
            acc[0][0] = __builtin_amdgcn_mfma_f32_16x16x32_bf16(a0, b0, acc[0][0], 0, 0, 0);
            acc[0][1] = __builtin_amdgcn_mfma_f32_16x16x32_bf16(a0, b1, acc[0][1], 0, 0, 0);
            acc[1][0] = __builtin_amdgcn_mfma_f32_16x16x32_bf16(a1, b0, acc[1][0], 0, 0, 0);
            acc[1][1] = __builtin_amdgcn_mfma_f32_16x16x32_bf16(a1, b1, acc[1][1], 0, 0, 0);
        }
        __syncthreads();
        cur ^= 1;
    }

    int row = m0 + wm + (lane >> 4) * 4;
    int col = n0 + wn + fr;
#pragma unroll
    for (int fm = 0; fm < 2; fm++)
#pragma unroll
        for (int fn = 0; fn < 2; fn++)
#pragma unroll
            for (int r = 0; r < 4; r++)
                atomicAdd(&Cacc[(size_t)(row + fm * 16 + r) * N + col + fn * 16],
                          acc[fm][fn][r]);
}

// ---------------------------------------------------------------------------
// FC2: single-K 64x64 GEMM with fused bias+relu+bf16 epilogue.
__global__ __launch_bounds__(256) void gemm_fc2_k(const unsigned short* __restrict__ A,
                                                  const unsigned short* __restrict__ W,
                                                  const float* __restrict__ bias,
                                                  unsigned short* __restrict__ dst,
                                                  int M, int N, int K) {
    __shared__ __align__(16) unsigned short As[2][8][64][8];
    __shared__ __align__(16) unsigned short Ws[2][8][64][8];

    int t = threadIdx.x;
    int lane = t & 63, wid = t >> 6;
    int m0 = blockIdx.y * 64, n0 = blockIdx.x * 64;
    int wm = (wid >> 1) * 32, wn = (wid & 1) * 32;
    int fr = lane & 15, kg = lane >> 4;
    int nsteps = K >> 6;

    f32x4 acc[2][2] = {};

    const unsigned short* Arow = A + (size_t)(m0 + lane) * K;
    const unsigned short* Wrow = W + (size_t)(n0 + lane) * K;

    auto stage = [&](int buf, int kb) {
#pragma unroll
        for (int i = 0; i < 2; i++) {
            int c = wid * 2 + i;
            __builtin_amdgcn_global_load_lds(
                (const __attribute__((address_space(1))) void*)(Arow + kb + c * 8),
                (__attribute__((address_space(3))) void*)(&As[buf][c][0][0]), 16, 0, 0);
            __builtin_amdgcn_global_load_lds(
                (const __attribute__((address_space(1))) void*)(Wrow + kb + c * 8),
                (__attribute__((address_space(3))) void*)(&Ws[buf][c][0][0]), 16, 0, 0);
        }
    };

    stage(0, 0);
    __syncthreads();
    int cur = 0;
    for (int tt = 0; tt < nsteps; ++tt) {
        if (tt + 1 < nsteps) stage(cur ^ 1, (tt + 1) * 64);
#pragma unroll
        for (int h = 0; h < 2; h++) {
            bf16x8 a0 = *(const bf16x8*)(&As[cur][h * 4 + kg][wm + fr][0]);
            bf16x8 a1 = *(const bf16x8*)(&As[cur][h * 4 + kg][wm + 16 + fr][0]);
            bf16x8 b0 = *(const bf16x8*)(&Ws[cur][h * 4 + kg][wn + fr][0]);
            bf16x8 b1 = *(const bf16x8*)(&Ws[cur][h * 4 + kg][wn + 16 + fr][0]);
            acc[0][0] = __builtin_amdgcn_mfma_f32_16x16x32_bf16(a0, b0, acc[0][0], 0, 0, 0);
            acc[0][1] = __builtin_amdgcn_mfma_f32_16x16x32_bf16(a0, b1, acc[0][1], 0, 0, 0);
            acc[1][0] = __builtin_amdgcn_mfma_f32_16x16x32_bf16(a1, b0, acc[1][0], 0, 0, 0);
            acc[1][1] = __builtin_amdgcn_mfma_f32_16x16x32_bf16(a1, b1, acc[1][1], 0, 0, 0);
        }
        __syncthreads();
        cur ^= 1;
    }

    int row = m0 + wm + (lane >> 4) * 4;
    int col = n0 + wn + fr;
#pragma unroll
    for (int fm = 0; fm < 2; fm++)
#pragma unroll
        for (int fn = 0; fn < 2; fn++) {
            float bv = bias[col + fn * 16];
#pragma unroll
            for (int r = 0; r < 4; r++) {
                float v = fmaxf(acc[fm][fn][r] + bv, 0.f);
                dst[(size_t)(row + fm * 16 + r) * N + col + fn * 16] = f2bf(v);
            }
        }
}

// ---------------------------------------------------------------------------
// FC1 GEMM: 128x128 tile, BK=64, single-buffer 32KB LDS m97 2-barrier loop,
// split-K 28 bf16 partials, tile-major XCD swizzle. grid = 896 blocks.
__global__ __launch_bounds__(256) void gemm128_bf16_k(const unsigned short* __restrict__ A,
                                                      const unsigned short* __restrict__ W,
                                                      unsigned short* __restrict__ Cp,
                                                      int M, int N, int K, int kchunk) {
    __shared__ __align__(16) unsigned short As[8][128][8];   // 16 KB
    __shared__ __align__(16) unsigned short Ws[8][128][8];   // 16 KB

    int lin  = blockIdx.x;
    int nb   = (lin & 7) * 112 + (lin >> 3);   // 896 = 8 XCD x 112, bijective
    int tile = nb / 28, bz = nb - tile * 28;   // z innermost per tile
    int bx = tile & 7, by = tile >> 3;

    int t = threadIdx.x;
    int lane = t & 63, wid = t >> 6;
    int m0 = by * 128, n0 = bx * 128;
    int k0 = bz * kchunk;
    int wm = (wid >> 1) * 64, wn = (wid & 1) * 64;
    int fr = lane & 15, kg = lane >> 4;

    f32x4 acc[4][4] = {};

    for (int kb = k0; kb < k0 + kchunk; kb += 64) {
#pragma unroll
        for (int i = 0; i < 4; i++) {
            int c   = wid * 4 + i;             // 0..15, wave-uniform
            int kgc = c >> 1;
            int r0w = (c & 1) * 64;
            __builtin_amdgcn_global_load_lds(
                (const __attribute__((address_space(1))) void*)
                    (A + (size_t)(m0 + r0w + lane) * K + kb + kgc * 8),
                (__attribute__((address_space(3))) void*)(&As[kgc][r0w][0]), 16, 0, 0);
            __builtin_amdgcn_global_load_lds(
                (const __attribute__((address_space(1))) void*)
                    (W + (size_t)(n0 + r0w + lane) * K + kb + kgc * 8),
                (__attribute__((address_space(3))) void*)(&Ws[kgc][r0w][0]), 16, 0, 0);
        }
        __syncthreads();
#pragma unroll
        for (int h = 0; h < 2; h++) {
            bf16x8 av[4], bv[4];
#pragma unroll
            for (int f = 0; f < 4; f++) {
                av[f] = *(const bf16x8*)(&As[h * 4 + kg][wm + f * 16 + fr][0]);
                bv[f] = *(const bf16x8*)(&Ws[h * 4 + kg][wn + f * 16 + fr][0]);
            }
#pragma unroll
            for (int fm = 0; fm < 4; fm++)
#pragma unroll
                for (int fn = 0; fn < 4; fn++)
                    acc[fm][fn] = __builtin_amdgcn_mfma_f32_16x16x32_bf16(
                        av[fm], bv[fn], acc[fm][fn], 0, 0, 0);
        }
        __syncthreads();
    }

    unsigned short* Cout = Cp + (size_t)bz * ((size_t)M * N);
    int row = m0 + wm + (lane >> 4) * 4;
    int col = n0 + wn + fr;
#pragma unroll
    for (int fm = 0; fm < 4; fm++)
#pragma unroll
        for (int fn = 0; fn < 4; fn++)
#pragma unroll
            for (int r = 0; r < 4; r++)
                Cout[(size_t)(row + fm * 16 + r) * N + col + fn * 16] =
                    f2bf(acc[fm][fn][r]);
}

// ---------------------------------------------------------------------------
// FC1 epilogue: sum 28 bf16 partial slices + bias + relu -> bf16.
__global__ __launch_bounds__(256) void fc_ep28_k(const unsigned short* __restrict__ Cp,
                                                 const float* __restrict__ bias,
                                                 unsigned short* __restrict__ dst,
                                                 int ks) {
    const int MN = NROI * HIDN;
    int i = blockIdx.x * 256 + threadIdx.x;        // 0 .. MN/4-1
    size_t base = (size_t)i * 4;
    float s0 = 0.f, s1 = 0.f, s2 = 0.f, s3 = 0.f;
    for (int p = 0; p < ks; p++) {
        ushort4 u = *(const ushort4*)(Cp + (size_t)p * MN + base);
        s0 += bf2f(u.x); s1 += bf2f(u.y); s2 += bf2f(u.z); s3 += bf2f(u.w);
    }
    int col = (int)(base & (HIDN - 1));
    ushort4 o;
    o.x = f2bf(fmaxf(s0 + bias[col + 0], 0.f));
    o.y = f2bf(fmaxf(s1 + bias[col + 1], 0.f));
    o.z = f2bf(fmaxf(s2 + bias[col + 2], 0.f));
    o.w = f2bf(fmaxf(s3 + bias[col + 3], 0.f));
    *(ushort4*)(dst + base) = o;
}

// head accumulator (512x512) -> bias + reg out + softmax(cls) out. Block = roi.
__global__ void head_ep_k(const float* __restrict__ hf,
                          const float* __restrict__ bc,
                          const float* __restrict__ br,
                          float* __restrict__ out) {
    int r = blockIdx.x, l = threadIdx.x;   // 64 threads
    const float* row = hf + (size_t)r * NHEAD;

    float* reg = out + OUT_ROIS + OUT_CLS + (size_t)r * NREG;
    for (int j = l; j < NREG; j += 64) reg[j] = row[NCLS + j] + br[j];

    float v0 = row[l] + bc[l];
    float v1 = (l + 64 < NCLS) ? row[l + 64] + bc[l + 64] : -INFINITY;
    float m = fmaxf(v0, v1);
#pragma unroll
    for (int o = 32; o; o >>= 1) m = fmaxf(m, __shfl_xor(m, o));
    float e0 = __expf(v0 - m);
    float e1 = (l + 64 < NCLS) ? __expf(v1 - m) : 0.f;
    float s = e0 + e1;
#pragma unroll
    for (int o = 32; o; o >>= 1) s += __shfl_xor(s, o);
    float inv = 1.f / s;
    float* cls = out + OUT_ROIS + (size_t)r * NCLS;
    cls[l] = e0 * inv;
    if (l + 64 < NCLS) cls[l + 64] = e1 * inv;
}

// ---------------------------------------------------------------------------
extern "C" void kernel_launch(void* const* d_in, const int* in_sizes, int n_in,
                              void* d_out, int out_size, void* d_ws, size_t ws_size,
                              hipStream_t stream) {
    const float* p2   = (const float*)d_in[0];
    const float* p3   = (const float*)d_in[1];
    const float* p4   = (const float*)d_in[2];
    const float* p5   = (const float*)d_in[3];
    const float* rois = (const float*)d_in[4];
    const float* w1   = (const float*)d_in[5];
    const float* b1   = (const float*)d_in[6];
    const float* w2   = (const float*)d_in[7];
    const float* b2   = (const float*)d_in[8];
    const float* wc   = (const float*)d_in[9];
    const float* bc   = (const float*)d_in[10];
    const float* wr   = (const float*)d_in[11];
    const float* br   = (const float*)d_in[12];

    float* out = (float*)d_out;

    const int KS1 = 28;   // FC1 split-K (12544 = 28 * 448)
    const int NPREP = 10 + 256 + 1024 + 1024 + 1024;   // 3338 prep blocks

    // workspace carve-up (256B-aligned chunks)
    char* p = (char*)d_ws;
    auto alloc = [&](size_t bytes) { char* r = p; p += (bytes + 255) & ~(size_t)255; return r; };
    unsigned short* xpool = (unsigned short*)alloc((size_t)NROI * DDIM * 2);    // 12.8 MB
    unsigned short* y1b   = (unsigned short*)alloc((size_t)NROI * HIDN * 2);
    unsigned short* y2b   = (unsigned short*)alloc((size_t)NROI * HIDN * 2);
    unsigned short* w1b   = (unsigned short*)alloc((size_t)HIDN * DDIM * 2);    // 25.7 MB
    unsigned short* w2b   = (unsigned short*)alloc((size_t)HIDN * HIDN * 2);
    unsigned short* whd   = (unsigned short*)alloc((size_t)NHEAD * HIDN * 2);
    float*          hf    = (float*)alloc((size_t)NROI * NHEAD * 4);            // 1 MB
    unsigned short* ft0 = (unsigned short*)alloc((size_t)2 * 40000 * CCH * 2);  // 41 MB
    unsigned short* ft1 = (unsigned short*)alloc((size_t)2 * 10000 * CCH * 2);
    unsigned short* ft2 = (unsigned short*)alloc((size_t)2 * 2500 * CCH * 2);
    unsigned short* ft3 = (unsigned short*)alloc((size_t)2 * 625 * CCH * 2);
    bool nhwc = (size_t)(p - (char*)d_ws) <= ws_size;

    // FC1 bf16 partials alias ft0 (features dead after roi_align; same-stream
    // order; transpose fully rewrites ft0 each call). 29.4 MB <= 41 MB.
    unsigned short* part = ft0;

    int ntrans = nhwc ? NTRANS : 0;
    fused_pre_k<<<ntrans + NPREP, 256, 0, stream>>>(
        p2, p3, p4, p5, ft0, ft1, ft2, ft3,
        rois, w1, w2, wc, wr, out, hf, w1b, w2b, whd, ntrans);

    if (nhwc) {
        roi_align_k<<<dim3(POOLP, NROI), 256, 0, stream>>>(ft0, ft1, ft2, ft3, rois, xpool);
    } else {
        roi_align_nchw_k<<<dim3(POOLP, NROI), 256, 0, stream>>>(p2, p3, p4, p5, rois, xpool);
    }

    // FC1: (512,12544)x(1024,12544)^T, 128^2 tile single-buf, split-K 28
    // bf16 partials, tile-major XCD swizzle
    gemm128_bf16_k<<<8 * 4 * KS1, 256, 0, stream>>>(
        xpool, w1b, part, NROI, HIDN, DDIM, DDIM / KS1);
    fc_ep28_k<<<(NROI * HIDN / 4 + 255) / 256, 256, 0, stream>>>(part, b1, y1b, KS1);

    // FC2: (512,1024)x(1024,1024)^T, single-K, fused bias+relu epilogue
    gemm_fc2_k<<<dim3(HIDN / 64, NROI / 64), 256, 0, stream>>>(
        y1b, w2b, b2, y2b, NROI, HIDN, HIDN);

    // head: (512,1024)x(512,1024)^T, split-K 4, atomic acc
    gemm_bf16_k<<<dim3(NHEAD / 64, NROI / 64, 4), 256, 0, stream>>>(
        y2b, whd, hf, NROI, NHEAD, HIDN, HIDN / 4);
    head_ep_k<<<NROI, 64, 0, stream>>>(hf, bc, br, out);
}